// Round 11
// baseline (8280.073 us; speedup 1.0000x reference)
//
#include <hip/hip_runtime.h>

// KNNGraph bruteforce-blas, euclidean, k=16, include self.
// x: (N=4, M=8192, D=64) fp32. Output: int32 src[N*M*K] then dst[N*M*K].
//
// VALIDATED reference model (R9, absmax=0 — numerics FROZEN):
//   x2  = np.sum(x*x,-1): squares rounded per-element, FLOAT_pairwise_sum
//         n=64 NPY_SIMD path: 4 vec accs (vstep=4), serial blocks,
//         combine (r0+r1)+(r2+r3), double-hadd (S0+S1)+(S2+S3).
//   dot = np.einsum baseline-SSE: per-16 block REVERSED muladd chain
//         v_l = p0l+(p1l+(p2l+(p3l+v_l))), double-hadd (v0+v1)+(v2+v3).
//   d2  = fl(fl(x2j+x2c) - fl(2*dot)); stable ties by lower index.
//
// R11: kill query-row REMATERIALIZATION (R10 post-mortem: VGPR=76 with no
// spill writes => compiler re-loads q from global per candidate; L2-latency
// bound). (1) amdgpu_waves_per_eu(2,2) pins 256-VGPR budget; (2) q held in
// 16 explicit float4 VGPR variables (no array => nothing to rematerialize).

#define MM 8192
#define NN 4
#define DD 64
#define KK 16
#define TK 20            // stage-A keep per chunk (16 + 4 safety margin)
#define TILE 64          // candidate tile rows staged in LDS
#define NROWS (NN * MM)  // 32768

// numpy SIMD pairwise sum of squares (SSE baseline), n=64. FROZEN.
__global__ __launch_bounds__(256) void norms_np_kernel(
    const float* __restrict__ x, float* __restrict__ x2) {
#pragma clang fp contract(off)
  int r = blockIdx.x * 256 + threadIdx.x;
  if (r >= NROWS) return;
  const float4* p = (const float4*)(x + (size_t)r * DD);
  float s[DD];
#pragma unroll
  for (int i = 0; i < DD / 4; ++i) {
    float4 v = p[i];
    s[4 * i + 0] = v.x * v.x;
    s[4 * i + 1] = v.y * v.y;
    s[4 * i + 2] = v.z * v.z;
    s[4 * i + 3] = v.w * v.w;
  }
  float acc[4][4];
#pragma unroll
  for (int c = 0; c < 4; ++c)
#pragma unroll
    for (int l = 0; l < 4; ++l) acc[c][l] = s[4 * c + l];
#pragma unroll
  for (int b = 1; b < 4; ++b)
#pragma unroll
    for (int c = 0; c < 4; ++c)
#pragma unroll
      for (int l = 0; l < 4; ++l)
        acc[c][l] = acc[c][l] + s[16 * b + 4 * c + l];
  float S[4];
#pragma unroll
  for (int l = 0; l < 4; ++l)
    S[l] = (acc[0][l] + acc[1][l]) + (acc[2][l] + acc[3][l]);
  x2[r] = (S[0] + S[1]) + (S[2] + S[3]);
}

// fast-path dot accumulate: 4 fma lanes on one float4 pair
#define DOT4(QQ, VV)                    \
  do {                                  \
    a0 = fmaf((QQ).x, (VV).x, a0);      \
    a1 = fmaf((QQ).y, (VV).y, a1);      \
    a2 = fmaf((QQ).z, (VV).z, a2);      \
    a3 = fmaf((QQ).w, (VV).w, a3);      \
  } while (0)

template <int P>
__global__ __launch_bounds__(256)
__attribute__((amdgpu_waves_per_eu(2, 2)))
void knn_partial_kernel(
    const float* __restrict__ x, const float* __restrict__ x2,
    int* __restrict__ pi) {
  __shared__ float tile[TILE * DD];   // 16 KB candidate tile
  __shared__ float x2t[TILE];         // x2 of the tile

  const int tid   = threadIdx.x;
  const int rb    = blockIdx.x / P;   // row-block 0..127
  const int chunk = blockIdx.x % P;   // candidate chunk
  const int b     = rb >> 5;          // batch (32 row-blocks per batch)
  const int row   = rb * 256 + tid;   // global row id
  const int j     = row - b * MM;     // row within batch

  const float* __restrict__ xb  = x + (size_t)b * MM * DD;  // uniform base
  const float* __restrict__ x2b = x2 + b * MM;              // uniform base

  // Query row in 16 explicit float4 registers (NOT an array: the R10
  // compiler rematerialized array loads into the K-loop).
  const float4* qp = (const float4*)(xb + (size_t)j * DD);
  float4 q0 = qp[0],  q1 = qp[1],  q2 = qp[2],  q3 = qp[3];
  float4 q4 = qp[4],  q5 = qp[5],  q6 = qp[6],  q7 = qp[7];
  float4 q8 = qp[8],  q9 = qp[9],  q10 = qp[10], q11 = qp[11];
  float4 q12 = qp[12], q13 = qp[13], q14 = qp[14], q15 = qp[15];

  float dist[TK];
  int   idx[TK];
#pragma unroll
  for (int t = 0; t < TK; ++t) {
    dist[t] = __builtin_inff();
    idx[t]  = 0x7fffffff;
  }

  const int C  = MM / P;
  const int c0 = chunk * C;

  for (int ts = c0; ts < c0 + C; ts += TILE) {
    __syncthreads();
    // Cooperative staging: TILE*DD floats = 1024 float4, 4 per thread.
    {
      const float4* gsrc = (const float4*)(xb + (size_t)ts * DD);
      float4* lds4 = (float4*)tile;
#pragma unroll
      for (int u = 0; u < 4; ++u) lds4[tid + 256 * u] = gsrc[tid + 256 * u];
      if (tid < TILE / 4)
        ((float4*)x2t)[tid] = ((const float4*)(x2b + ts))[tid];
    }
    __syncthreads();

    for (int t = 0; t < TILE; ++t) {
      const float4* cp = (const float4*)(tile + t * DD);  // broadcast reads
      float a0 = 0.f, a1 = 0.f, a2 = 0.f, a3 = 0.f;
      DOT4(q0,  cp[0]);  DOT4(q1,  cp[1]);  DOT4(q2,  cp[2]);  DOT4(q3,  cp[3]);
      DOT4(q4,  cp[4]);  DOT4(q5,  cp[5]);  DOT4(q6,  cp[6]);  DOT4(q7,  cp[7]);
      DOT4(q8,  cp[8]);  DOT4(q9,  cp[9]);  DOT4(q10, cp[10]); DOT4(q11, cp[11]);
      DOT4(q12, cp[12]); DOT4(q13, cp[13]); DOT4(q14, cp[14]); DOT4(q15, cp[15]);
      float dot = (a0 + a1) + (a2 + a3);
      float key = fmaf(-2.f, dot, x2t[t]);  // heuristic rank key

      if (key < dist[TK - 1]) {
        dist[TK - 1] = key;
        idx[TK - 1]  = ts + t;
#pragma unroll
        for (int t2 = TK - 1; t2 > 0; --t2) {
          bool sw = dist[t2] < dist[t2 - 1];
          float dlo = sw ? dist[t2] : dist[t2 - 1];
          float dhi = sw ? dist[t2 - 1] : dist[t2];
          int   ilo = sw ? idx[t2] : idx[t2 - 1];
          int   ihi = sw ? idx[t2 - 1] : idx[t2];
          dist[t2 - 1] = dlo; dist[t2] = dhi;
          idx[t2 - 1]  = ilo; idx[t2]  = ihi;
        }
      }
    }
  }

  size_t base = ((size_t)row * P + chunk) * TK;
#pragma unroll
  for (int t = 0; t < TK; ++t) pi[base + t] = idx[t];
}

// FROZEN-numerics einsum block: per-product rounding then reversed adds.
#define EBLK(QA, QB, QC, QD, W0, W1, W2, W3)                                  \
  do {                                                                        \
    v0 = (QA).x * (W0).x +                                                    \
         ((QB).x * (W1).x + ((QC).x * (W2).x + ((QD).x * (W3).x + v0)));      \
    v1 = (QA).y * (W0).y +                                                    \
         ((QB).y * (W1).y + ((QC).y * (W2).y + ((QD).y * (W3).y + v1)));      \
    v2 = (QA).z * (W0).z +                                                    \
         ((QB).z * (W1).z + ((QC).z * (W2).z + ((QD).z * (W3).z + v2)));      \
    v3 = (QA).w * (W0).w +                                                    \
         ((QB).w * (W1).w + ((QC).w * (W2).w + ((QD).w * (W3).w + v3)));      \
  } while (0)

template <int P>
__global__ __launch_bounds__(256)
__attribute__((amdgpu_waves_per_eu(2, 2)))
void knn_rescore_kernel(
    const float* __restrict__ x, const float* __restrict__ x2,
    const int* __restrict__ pi,
    int* __restrict__ src, int* __restrict__ dst) {
#pragma clang fp contract(off)
  int r = blockIdx.x * 256 + threadIdx.x;
  if (r >= NROWS) return;
  const int b = r >> 13;          // / MM
  const int j = r & (MM - 1);     // row within batch
  const float* __restrict__ xb = x + (size_t)b * MM * DD;
  const float x2j = x2[r];

  const float4* qp = (const float4*)(xb + (size_t)j * DD);
  float4 q0 = qp[0],  q1 = qp[1],  q2 = qp[2],  q3 = qp[3];
  float4 q4 = qp[4],  q5 = qp[5],  q6 = qp[6],  q7 = qp[7];
  float4 q8 = qp[8],  q9 = qp[9],  q10 = qp[10], q11 = qp[11];
  float4 q12 = qp[12], q13 = qp[13], q14 = qp[14], q15 = qp[15];

  float bd[KK];
  int   bi[KK];
#pragma unroll
  for (int t = 0; t < KK; ++t) {
    bd[t] = __builtin_inff();
    bi[t] = 0x7fffffff;
  }

  const int CAND = P * TK;
  size_t base = (size_t)r * CAND;

  for (int t = 0; t < CAND; ++t) {
    int c = pi[base + t];
    const float4* pp = (const float4*)(xb + (size_t)c * DD);
    // FROZEN numerics: einsum baseline-SSE reversed muladd chain,
    // per 16-elem block, then double-hadd. Same expression tree as R9.
    float v0 = 0.f, v1 = 0.f, v2 = 0.f, v3 = 0.f;
    {
      float4 w0 = pp[0], w1 = pp[1], w2 = pp[2], w3 = pp[3];
      EBLK(q0, q1, q2, q3, w0, w1, w2, w3);
    }
    {
      float4 w0 = pp[4], w1 = pp[5], w2 = pp[6], w3 = pp[7];
      EBLK(q4, q5, q6, q7, w0, w1, w2, w3);
    }
    {
      float4 w0 = pp[8], w1 = pp[9], w2 = pp[10], w3 = pp[11];
      EBLK(q8, q9, q10, q11, w0, w1, w2, w3);
    }
    {
      float4 w0 = pp[12], w1 = pp[13], w2 = pp[14], w3 = pp[15];
      EBLK(q12, q13, q14, q15, w0, w1, w2, w3);
    }
    float dotf = (v0 + v1) + (v2 + v3);
    float s  = x2j + x2[b * MM + c];
    float tm = 2.0f * dotf;
    float d2 = s - tm;

    bool lt = (d2 < bd[KK - 1]) ||
              (d2 == bd[KK - 1] && c < bi[KK - 1]);
    if (lt) {
      bd[KK - 1] = d2;
      bi[KK - 1] = c;
#pragma unroll
      for (int t2 = KK - 1; t2 > 0; --t2) {
        bool sw = (bd[t2] < bd[t2 - 1]) ||
                  (bd[t2] == bd[t2 - 1] && bi[t2] < bi[t2 - 1]);
        float dlo = sw ? bd[t2] : bd[t2 - 1];
        float dhi = sw ? bd[t2 - 1] : bd[t2];
        int   ilo = sw ? bi[t2] : bi[t2 - 1];
        int   ihi = sw ? bi[t2 - 1] : bi[t2];
        bd[t2 - 1] = dlo; bd[t2] = dhi;
        bi[t2 - 1] = ilo; bi[t2] = ihi;
      }
    }
  }

#pragma unroll
  for (int t = 0; t < KK; ++t) {
    src[(size_t)r * KK + t] = b * MM + bi[t];
    dst[(size_t)r * KK + t] = r;
  }
}

template <int P>
static void launch_all(const float* x, int* out, void* d_ws, hipStream_t stream) {
  char* ws = (char*)d_ws;
  float* x2 = (float*)ws;
  int*   pi = (int*)(ws + (size_t)NROWS * sizeof(float));

  int* src = out;
  int* dst = out + (size_t)NROWS * KK;

  norms_np_kernel<<<NROWS / 256, 256, 0, stream>>>(x, x2);
  knn_partial_kernel<P><<<(NROWS / 256) * P, 256, 0, stream>>>(x, x2, pi);
  knn_rescore_kernel<P><<<NROWS / 256, 256, 0, stream>>>(x, x2, pi, src, dst);
}

extern "C" void kernel_launch(void* const* d_in, const int* in_sizes, int n_in,
                              void* d_out, int out_size, void* d_ws, size_t ws_size,
                              hipStream_t stream) {
  const float* x = (const float*)d_in[0];
  int* out = (int*)d_out;

  auto need = [](int P) {
    return (size_t)NROWS * sizeof(float) +
           (size_t)NROWS * P * TK * sizeof(int);
  };

  if (ws_size >= need(4)) {
    launch_all<4>(x, out, d_ws, stream);
  } else if (ws_size >= need(2)) {
    launch_all<2>(x, out, d_ws, stream);
  } else {
    launch_all<1>(x, out, d_ws, stream);
  }
}

// Round 12
// 1759.982 us; speedup vs baseline: 4.7046x; 4.7046x over previous
//
#include <hip/hip_runtime.h>

// KNNGraph bruteforce-blas, euclidean, k=16, include self.
// x: (N=4, M=8192, D=64) fp32. Output: int32 src[N*M*K] then dst[N*M*K].
//
// VALIDATED reference model (R9, absmax=0 — numerics FROZEN):
//   x2  = np.sum(x*x,-1): squares rounded per-element, FLOAT_pairwise_sum
//         n=64 NPY_SIMD path: 4 vec accs (vstep=4), serial blocks,
//         combine (r0+r1)+(r2+r3), double-hadd (S0+S1)+(S2+S3).
//   dot = np.einsum baseline-SSE: per-16 block REVERSED muladd chain
//         v_l = p0l+(p1l+(p2l+(p3l+v_l))), double-hadd (v0+v1)+(v2+v3).
//   d2  = fl(fl(x2j+x2c) - fl(2*dot)); stable ties by lower index.
//
// R12: R11 post-mortem showed ~1800 VALU instr/candidate (10x source) —
// compiler-expanded selection (arrays demoted). Fix: selection state in 40
// EXPLICIT named scalars, branchless straight-line bubble (1 select + 19
// compare-swaps, every candidate). Nothing for the compiler to demote.

#define MM 8192
#define NN 4
#define DD 64
#define KK 16
#define TK 20            // stage-A keep per chunk (16 + 4 safety margin)
#define TILE 64          // candidate tile rows staged in LDS
#define NROWS (NN * MM)  // 32768

// numpy SIMD pairwise sum of squares (SSE baseline), n=64. FROZEN.
__global__ __launch_bounds__(256) void norms_np_kernel(
    const float* __restrict__ x, float* __restrict__ x2) {
#pragma clang fp contract(off)
  int r = blockIdx.x * 256 + threadIdx.x;
  if (r >= NROWS) return;
  const float4* p = (const float4*)(x + (size_t)r * DD);
  float s[DD];
#pragma unroll
  for (int i = 0; i < DD / 4; ++i) {
    float4 v = p[i];
    s[4 * i + 0] = v.x * v.x;
    s[4 * i + 1] = v.y * v.y;
    s[4 * i + 2] = v.z * v.z;
    s[4 * i + 3] = v.w * v.w;
  }
  float acc[4][4];
#pragma unroll
  for (int c = 0; c < 4; ++c)
#pragma unroll
    for (int l = 0; l < 4; ++l) acc[c][l] = s[4 * c + l];
#pragma unroll
  for (int b = 1; b < 4; ++b)
#pragma unroll
    for (int c = 0; c < 4; ++c)
#pragma unroll
      for (int l = 0; l < 4; ++l)
        acc[c][l] = acc[c][l] + s[16 * b + 4 * c + l];
  float S[4];
#pragma unroll
  for (int l = 0; l < 4; ++l)
    S[l] = (acc[0][l] + acc[1][l]) + (acc[2][l] + acc[3][l]);
  x2[r] = (S[0] + S[1]) + (S[2] + S[3]);
}

// fast-path dot accumulate: 4 fma lanes on one float4 pair
#define DOT4(QQ, VV)                    \
  do {                                  \
    a0 = fmaf((QQ).x, (VV).x, a0);      \
    a1 = fmaf((QQ).y, (VV).y, a1);      \
    a2 = fmaf((QQ).z, (VV).z, a2);      \
    a3 = fmaf((QQ).w, (VV).w, a3);      \
  } while (0)

// Branchless compare-swap of adjacent selection slots (strict <: stable).
#define BSTEP(dA, iA, dB, iB)              \
  do {                                     \
    bool s_ = (dB) < (dA);                 \
    float tlo = s_ ? (dB) : (dA);          \
    float thi = s_ ? (dA) : (dB);          \
    int   jlo = s_ ? (iB) : (iA);          \
    int   jhi = s_ ? (iA) : (iB);          \
    (dA) = tlo; (dB) = thi;                \
    (iA) = jlo; (iB) = jhi;                \
  } while (0)

template <int P>
__global__ __launch_bounds__(256)
__attribute__((amdgpu_waves_per_eu(2, 2)))
void knn_partial_kernel(
    const float* __restrict__ x, const float* __restrict__ x2,
    int* __restrict__ pi) {
  __shared__ float tile[TILE * DD];   // 16 KB candidate tile
  __shared__ float x2t[TILE];         // x2 of the tile

  const int tid   = threadIdx.x;
  const int rb    = blockIdx.x / P;   // row-block 0..127
  const int chunk = blockIdx.x % P;   // candidate chunk
  const int b     = rb >> 5;          // batch (32 row-blocks per batch)
  const int row   = rb * 256 + tid;   // global row id
  const int j     = row - b * MM;     // row within batch

  const float* __restrict__ xb  = x + (size_t)b * MM * DD;  // uniform base
  const float* __restrict__ x2b = x2 + b * MM;              // uniform base

  // Query row in 16 explicit float4 registers.
  const float4* qp = (const float4*)(xb + (size_t)j * DD);
  float4 q0 = qp[0],  q1 = qp[1],  q2 = qp[2],  q3 = qp[3];
  float4 q4 = qp[4],  q5 = qp[5],  q6 = qp[6],  q7 = qp[7];
  float4 q8 = qp[8],  q9 = qp[9],  q10 = qp[10], q11 = qp[11];
  float4 q12 = qp[12], q13 = qp[13], q14 = qp[14], q15 = qp[15];

  // Selection state: 20 sorted (key, idx) pairs in EXPLICIT scalars.
  const float INF = __builtin_inff();
  float d0 = INF, d1 = INF, d2 = INF, d3 = INF, d4 = INF;
  float d5 = INF, d6 = INF, d7 = INF, d8 = INF, d9 = INF;
  float d10 = INF, d11 = INF, d12 = INF, d13 = INF, d14 = INF;
  float d15 = INF, d16 = INF, d17 = INF, d18 = INF, d19 = INF;
  int i0 = 0, i1 = 0, i2 = 0, i3 = 0, i4 = 0;
  int i5 = 0, i6 = 0, i7 = 0, i8 = 0, i9 = 0;
  int i10 = 0, i11 = 0, i12 = 0, i13 = 0, i14 = 0;
  int i15 = 0, i16 = 0, i17 = 0, i18 = 0, i19 = 0;

  const int C  = MM / P;
  const int c0 = chunk * C;

  for (int ts = c0; ts < c0 + C; ts += TILE) {
    __syncthreads();
    // Cooperative staging: TILE*DD floats = 1024 float4, 4 per thread.
    {
      const float4* gsrc = (const float4*)(xb + (size_t)ts * DD);
      float4* lds4 = (float4*)tile;
#pragma unroll
      for (int u = 0; u < 4; ++u) lds4[tid + 256 * u] = gsrc[tid + 256 * u];
      if (tid < TILE / 4)
        ((float4*)x2t)[tid] = ((const float4*)(x2b + ts))[tid];
    }
    __syncthreads();

#pragma unroll 2
    for (int t = 0; t < TILE; ++t) {
      const float4* cp = (const float4*)(tile + t * DD);  // broadcast reads
      float a0 = 0.f, a1 = 0.f, a2 = 0.f, a3 = 0.f;
      DOT4(q0,  cp[0]);  DOT4(q1,  cp[1]);  DOT4(q2,  cp[2]);  DOT4(q3,  cp[3]);
      DOT4(q4,  cp[4]);  DOT4(q5,  cp[5]);  DOT4(q6,  cp[6]);  DOT4(q7,  cp[7]);
      DOT4(q8,  cp[8]);  DOT4(q9,  cp[9]);  DOT4(q10, cp[10]); DOT4(q11, cp[11]);
      DOT4(q12, cp[12]); DOT4(q13, cp[13]); DOT4(q14, cp[14]); DOT4(q15, cp[15]);
      float dot = (a0 + a1) + (a2 + a3);
      float key = fmaf(-2.f, dot, x2t[t]);  // heuristic rank key

      // Branchless insert: replace worst if better, bubble to place.
      bool ins = key < d19;
      d19 = ins ? key : d19;
      i19 = ins ? (ts + t) : i19;
      BSTEP(d18, i18, d19, i19);
      BSTEP(d17, i17, d18, i18);
      BSTEP(d16, i16, d17, i17);
      BSTEP(d15, i15, d16, i16);
      BSTEP(d14, i14, d15, i15);
      BSTEP(d13, i13, d14, i14);
      BSTEP(d12, i12, d13, i13);
      BSTEP(d11, i11, d12, i12);
      BSTEP(d10, i10, d11, i11);
      BSTEP(d9,  i9,  d10, i10);
      BSTEP(d8,  i8,  d9,  i9);
      BSTEP(d7,  i7,  d8,  i8);
      BSTEP(d6,  i6,  d7,  i7);
      BSTEP(d5,  i5,  d6,  i6);
      BSTEP(d4,  i4,  d5,  i5);
      BSTEP(d3,  i3,  d4,  i4);
      BSTEP(d2,  i2,  d3,  i3);
      BSTEP(d1,  i1,  d2,  i2);
      BSTEP(d0,  i0,  d1,  i1);
    }
  }

  size_t base = ((size_t)row * P + chunk) * TK;
  pi[base + 0]  = i0;  pi[base + 1]  = i1;  pi[base + 2]  = i2;
  pi[base + 3]  = i3;  pi[base + 4]  = i4;  pi[base + 5]  = i5;
  pi[base + 6]  = i6;  pi[base + 7]  = i7;  pi[base + 8]  = i8;
  pi[base + 9]  = i9;  pi[base + 10] = i10; pi[base + 11] = i11;
  pi[base + 12] = i12; pi[base + 13] = i13; pi[base + 14] = i14;
  pi[base + 15] = i15; pi[base + 16] = i16; pi[base + 17] = i17;
  pi[base + 18] = i18; pi[base + 19] = i19;
}

// FROZEN-numerics einsum block: per-product rounding then reversed adds.
#define EBLK(QA, QB, QC, QD, W0, W1, W2, W3)                                  \
  do {                                                                        \
    v0 = (QA).x * (W0).x +                                                    \
         ((QB).x * (W1).x + ((QC).x * (W2).x + ((QD).x * (W3).x + v0)));      \
    v1 = (QA).y * (W0).y +                                                    \
         ((QB).y * (W1).y + ((QC).y * (W2).y + ((QD).y * (W3).y + v1)));      \
    v2 = (QA).z * (W0).z +                                                    \
         ((QB).z * (W1).z + ((QC).z * (W2).z + ((QD).z * (W3).z + v2)));      \
    v3 = (QA).w * (W0).w +                                                    \
         ((QB).w * (W1).w + ((QC).w * (W2).w + ((QD).w * (W3).w + v3)));      \
  } while (0)

template <int P>
__global__ __launch_bounds__(256)
__attribute__((amdgpu_waves_per_eu(2, 2)))
void knn_rescore_kernel(
    const float* __restrict__ x, const float* __restrict__ x2,
    const int* __restrict__ pi,
    int* __restrict__ src, int* __restrict__ dst) {
#pragma clang fp contract(off)
  int r = blockIdx.x * 256 + threadIdx.x;
  if (r >= NROWS) return;
  const int b = r >> 13;          // / MM
  const int j = r & (MM - 1);     // row within batch
  const float* __restrict__ xb = x + (size_t)b * MM * DD;
  const float x2j = x2[r];

  const float4* qp = (const float4*)(xb + (size_t)j * DD);
  float4 q0 = qp[0],  q1 = qp[1],  q2 = qp[2],  q3 = qp[3];
  float4 q4 = qp[4],  q5 = qp[5],  q6 = qp[6],  q7 = qp[7];
  float4 q8 = qp[8],  q9 = qp[9],  q10 = qp[10], q11 = qp[11];
  float4 q12 = qp[12], q13 = qp[13], q14 = qp[14], q15 = qp[15];

  float bd[KK];
  int   bi[KK];
#pragma unroll
  for (int t = 0; t < KK; ++t) {
    bd[t] = __builtin_inff();
    bi[t] = 0x7fffffff;
  }

  const int CAND = P * TK;
  size_t base = (size_t)r * CAND;

  for (int t = 0; t < CAND; ++t) {
    int c = pi[base + t];
    const float4* pp = (const float4*)(xb + (size_t)c * DD);
    // FROZEN numerics: einsum baseline-SSE reversed muladd chain.
    float v0 = 0.f, v1 = 0.f, v2 = 0.f, v3 = 0.f;
    {
      float4 w0 = pp[0], w1 = pp[1], w2 = pp[2], w3 = pp[3];
      EBLK(q0, q1, q2, q3, w0, w1, w2, w3);
    }
    {
      float4 w0 = pp[4], w1 = pp[5], w2 = pp[6], w3 = pp[7];
      EBLK(q4, q5, q6, q7, w0, w1, w2, w3);
    }
    {
      float4 w0 = pp[8], w1 = pp[9], w2 = pp[10], w3 = pp[11];
      EBLK(q8, q9, q10, q11, w0, w1, w2, w3);
    }
    {
      float4 w0 = pp[12], w1 = pp[13], w2 = pp[14], w3 = pp[15];
      EBLK(q12, q13, q14, q15, w0, w1, w2, w3);
    }
    float dotf = (v0 + v1) + (v2 + v3);
    float s  = x2j + x2[b * MM + c];
    float tm = 2.0f * dotf;
    float d2 = s - tm;

    bool lt = (d2 < bd[KK - 1]) ||
              (d2 == bd[KK - 1] && c < bi[KK - 1]);
    if (lt) {
      bd[KK - 1] = d2;
      bi[KK - 1] = c;
#pragma unroll
      for (int t2 = KK - 1; t2 > 0; --t2) {
        bool sw = (bd[t2] < bd[t2 - 1]) ||
                  (bd[t2] == bd[t2 - 1] && bi[t2] < bi[t2 - 1]);
        float dlo = sw ? bd[t2] : bd[t2 - 1];
        float dhi = sw ? bd[t2 - 1] : bd[t2];
        int   ilo = sw ? bi[t2] : bi[t2 - 1];
        int   ihi = sw ? bi[t2 - 1] : bi[t2];
        bd[t2 - 1] = dlo; bd[t2] = dhi;
        bi[t2 - 1] = ilo; bi[t2] = ihi;
      }
    }
  }

#pragma unroll
  for (int t = 0; t < KK; ++t) {
    src[(size_t)r * KK + t] = b * MM + bi[t];
    dst[(size_t)r * KK + t] = r;
  }
}

template <int P>
static void launch_all(const float* x, int* out, void* d_ws, hipStream_t stream) {
  char* ws = (char*)d_ws;
  float* x2 = (float*)ws;
  int*   pi = (int*)(ws + (size_t)NROWS * sizeof(float));

  int* src = out;
  int* dst = out + (size_t)NROWS * KK;

  norms_np_kernel<<<NROWS / 256, 256, 0, stream>>>(x, x2);
  knn_partial_kernel<P><<<(NROWS / 256) * P, 256, 0, stream>>>(x, x2, pi);
  knn_rescore_kernel<P><<<NROWS / 256, 256, 0, stream>>>(x, x2, pi, src, dst);
}

extern "C" void kernel_launch(void* const* d_in, const int* in_sizes, int n_in,
                              void* d_out, int out_size, void* d_ws, size_t ws_size,
                              hipStream_t stream) {
  const float* x = (const float*)d_in[0];
  int* out = (int*)d_out;

  auto need = [](int P) {
    return (size_t)NROWS * sizeof(float) +
           (size_t)NROWS * P * TK * sizeof(int);
  };

  if (ws_size >= need(4)) {
    launch_all<4>(x, out, d_ws, stream);
  } else if (ws_size >= need(2)) {
    launch_all<2>(x, out, d_ws, stream);
  } else {
    launch_all<1>(x, out, d_ws, stream);
  }
}